// Round 8
// baseline (402.192 us; speedup 1.0000x reference)
//
#include <hip/hip_runtime.h>
#include <math.h>

#define L_C 1024
#define B_C 32
#define F_C 24
#define S_C 12
#define N_C (L_C*B_C)   // 32768
#define DWIN 20
#define GRID_FZ 1536    // 6 blocks/CU (LDS 25344B/block) -> 24 waves/CU
#define NGRP (N_C/4)    // 8192 groups of 4 n (block = 4 waves, wave = 1 n/iter)

// ---------------------------------------------------------------------------
// Kernel A: windowed Gaussian message passing, F and S in one launch.
// ---------------------------------------------------------------------------
__global__ void msg_all(const float* __restrict__ f, const float* __restrict__ s,
                        float* __restrict__ fmp, float* __restrict__ fmf,
                        float* __restrict__ smp, float* __restrict__ smf) {
    int idx = blockIdx.x * 256 + threadIdx.x;
    const float* x; float *mp, *mf; int stride, i;
    if (idx < N_C * F_C) { x = f; mp = fmp; mf = fmf; stride = B_C*F_C; i = idx; }
    else { x = s; mp = smp; mf = smf; stride = B_C*S_C; i = idx - N_C*F_C; }
    int t = i / stride;
    float accp = 0.f, accf = 0.f;
    #pragma unroll
    for (int d = 1; d <= DWIN; ++d) {
        float w = expf(-0.125f * (float)(d * d));
        if (t >= d)      accp += w * x[i - d * stride];
        if (t + d < L_C) accf += w * x[i + d * stride];
    }
    mp[i] = accp / fmaxf((float)t, 1.0f);
    mf[i] = accf / fmaxf((float)(L_C - 1 - t), 1.0f);
}

__device__ inline float segred_max(float v) {
    #pragma unroll
    for (int o = 16; o >= 1; o >>= 1) v = fmaxf(v, __shfl_xor(v, o, 32));
    return v;
}
__device__ inline float segred_sum(float v) {
    #pragma unroll
    for (int o = 16; o >= 1; o >>= 1) v += __shfl_xor(v, o, 32);
    return v;
}

// ---------------------------------------------------------------------------
// Kernel B v8: wave-private LDS, zero barriers, fully-coalesced HBM traffic.
// Block = 4 waves; wave w owns n = (bid + it*GRID_FZ)*4 + w, persistent.
// Per iter:
//   [wait own vmcnt(0): staging landed]
//   rows from LDS slice:  P2 6x ds_read_b128, P4 3x b128, P5 24x b32
//   cols direct global (coalesced, L2-hot): P1 24x b32, P3 12x b32
//   [lgkmcnt(0)] stage(n+1) via 7x global_load_lds (overlaps tail)
//   softmax(orig)+softmax(next)+all 5 loss terms+outputs  (tail)
// LDS slice floats: ff@0(576) fs@576(288) fst@864(288) sft@1152(288) ss@1440(144)
// ---------------------------------------------------------------------------
__global__ __launch_bounds__(256, 6) void fuse_kernel(
    const float* __restrict__ f,  const float* __restrict__ s,
    const float* __restrict__ fs, const float* __restrict__ ff,
    const float* __restrict__ ss, const float* __restrict__ fst,
    const float* __restrict__ sft,
    const int* __restrict__ fl, const int* __restrict__ sl,
    const int* __restrict__ yl, const int* __restrict__ y2f,
    const int* __restrict__ y2s,
    const float* __restrict__ fmp, const float* __restrict__ fmf,
    const float* __restrict__ smp, const float* __restrict__ smf,
    float* __restrict__ outf, float* __restrict__ outs,
    float* __restrict__ part)
{
    __shared__ float Lf[4*1584];    // 25344 B: 4 wave-private 6336B slices
    char* LB = (char*)Lf;

    const int tid  = threadIdx.x;
    const int w    = tid >> 6;
    const int lane = tid & 63;
    const int bid  = blockIdx.x;
    float* Lw = Lf + w*1584;

    // ---- staging sources: 7 named (ptr, stride) pairs; per-n f4 stream:
    //      [0,144) ff | [144,216) fs | [216,288) fst | [288,360) sft | [360,396) ss
    const char *p0,*p1,*p2,*p3,*p4,*p5,*p6;
    long t0,t1,t2,t3,t4,t5,t6;
    {
        const int n0 = bid*4 + w;
        auto mk = [&](int j, const char*& P, long& S) {
            int i = 64*j + lane; if (i > 395) i = 395;
            const float* base; int off, af4;
            if (i < 144)      { base = ff;  off = i;       af4 = 144; }
            else if (i < 216) { base = fs;  off = i - 144; af4 = 72;  }
            else if (i < 288) { base = fst; off = i - 216; af4 = 72;  }
            else if (i < 360) { base = sft; off = i - 288; af4 = 72;  }
            else              { base = ss;  off = i - 360; af4 = 36;  }
            P = (const char*)base + ((size_t)n0*af4 + off)*16;
            S = (long)af4 * (GRID_FZ*4) * 16;
        };
        mk(0,p0,t0); mk(1,p1,t1); mk(2,p2,t2); mk(3,p3,t3);
        mk(4,p4,t4); mk(5,p5,t5); mk(6,p6,t6);
    }

    #define ISSUE(J, PJ) \
        __builtin_amdgcn_global_load_lds( \
            (const __attribute__((address_space(1))) void*)(PJ), \
            (__attribute__((address_space(3))) void*)(LB + w*6336 + (J)*1024), \
            16, 0, 0)
    #define STAGE() do { \
        ISSUE(0,p0); ISSUE(1,p1); ISSUE(2,p2); ISSUE(3,p3); ISSUE(4,p4); ISSUE(5,p5); \
        if (lane < 12) { ISSUE(6,p6); } \
        p0+=t0; p1+=t1; p2+=t2; p3+=t3; p4+=t4; p5+=t5; p6+=t6; \
    } while(0)

    const bool isF    = lane < 32;
    const bool active = (lane < 24) | (lane >= 32 && lane < 44);
    const int gg = (lane < 24) ? lane : 23;
    const int tt = ((lane & 31) < 12) ? (lane & 31) : 11;

    // loop-invariant LDS addresses
    const float4* r2 = (const float4*)(Lw + (isF ? 24*gg : 1152 + 24*tt));
    const float4* r4 = (const float4*)(Lw + (isF ? 864 + 12*gg : 1440 + 12*tt));
    const float* a5_0 = Lw + (isF ? 576 + 12*gg : 576 + tt);
    const int i5a = isF ? 1 : 12;      // P5 increment k<11
    const int i5b = isF ? 0 : 12;      // P5 increment k>=11
    const int st1 = isF ? 96 : 48;     // P1 global col stride (bytes)
    const int st3 = isF ? 96 : 48;     // P3 global col stride

    const int niter = (NGRP - bid + GRID_FZ - 1) / GRID_FZ;
    STAGE();   // group 0 for this wave

    for (int it = 0; it < niter; ++it) {
        const int nu = __builtin_amdgcn_readfirstlane((bid + it*GRID_FZ)*4 + w);

        // wave-uniform vectors (SMEM scalar loads)
        const float* vmpf = fmp + (size_t)nu*24;
        const float* vmff = fmf + (size_t)nu*24;
        const float* vmps = smp + (size_t)nu*12;
        const float* vmfs = smf + (size_t)nu*12;
        const float* vF   = f   + (size_t)nu*24;
        const float* vS   = s   + (size_t)nu*12;

        // own staging landed
        asm volatile("s_waitcnt vmcnt(0)" ::: "memory");
        __builtin_amdgcn_sched_barrier(0);

        float acc0 = 0.f, acc1 = 0.f, acc2 = 0.f, acc3 = 0.f;

        // P2 (LDS rows): {ff[g,:] | sft[t,:]} . vmff
        #pragma unroll
        for (int j = 0; j < 6; ++j) {
            float4 a = r2[j];
            acc1 += a.x*vmff[4*j] + a.y*vmff[4*j+1] + a.z*vmff[4*j+2] + a.w*vmff[4*j+3];
        }
        // P4 (LDS rows): {fst[g,:] | ss[t,:]} . vmfs
        #pragma unroll
        for (int j = 0; j < 3; ++j) {
            float4 a = r4[j];
            acc3 += a.x*vmfs[4*j] + a.y*vmfs[4*j+1] + a.z*vmfs[4*j+2] + a.w*vmfs[4*j+3];
        }
        // P5 (LDS, uniform 24 steps): f: fs[g,k<12].vs | s: fs[k,t].vf
        {
            const float* a5 = a5_0;
            #pragma unroll
            for (int k = 0; k < 24; ++k) {
                float m = isF ? ((k < 12) ? vS[k] : 0.0f) : vF[k];
                acc2 += m * (*a5);
                if (k < 23) a5 += (k < 11) ? i5a : i5b;
            }
        }
        // P1 (global cols, coalesced, L2-hot): vmpf . {ff[:,g] | fst[:,t]}
        {
            const char* q = isF ? (const char*)(ff  + (size_t)nu*576 + gg)
                                : (const char*)(fst + (size_t)nu*288 + tt);
            #pragma unroll
            for (int k = 0; k < 24; ++k) {
                acc0 += vmpf[k] * *(const float*)q;
                q += st1;
            }
        }
        // P3 (global cols): vmps . {sft[:,g] | ss[:,t]}
        {
            const char* q = isF ? (const char*)(sft + (size_t)nu*288 + gg)
                                : (const char*)(ss  + (size_t)nu*144 + tt);
            #pragma unroll
            for (int k = 0; k < 12; ++k) {
                acc3 += vmps[k] * *(const float*)q;
                q += st3;
            }
        }

        // per-lane original logit
        float fval = 0.f;
        if (lane < 24)                    fval = vF[lane];
        else if (lane >= 32 && lane < 44) fval = vS[lane - 32];

        float acc = (acc0 + acc1) + (acc2 + acc3);
        float nx = fval + 0.5f * acc;
        float xo = active ? fval : -INFINITY;
        float xn = active ? nx   : -INFINITY;

        // all LDS reads retired -> safe to overwrite slice; issue next stage
        asm volatile("s_waitcnt lgkmcnt(0)" ::: "memory");
        __builtin_amdgcn_sched_barrier(0);
        if (it + 1 < niter) STAGE();

        // ---- tail (overlaps staging latency) ----
        float mo = segred_max(xo);
        float eo = expf(xo - mo);
        float so = segred_sum(eo);
        float lse_o = mo + logf(so);

        float mn = segred_max(xn);
        float en = expf(xn - mn);
        float sn = segred_sum(en);
        float pr = en / sn;
        float lse_n = mn + logf(sn);

        const size_t nn = (size_t)nu;
        if (lane < 24)                    outf[nn*24 + lane]        = pr;
        else if (lane >= 32 && lane < 44) outs[nn*12 + (lane - 32)] = pr;

        const int fln = fl[nu], sln = sl[nu], yln = yl[nu];
        const int yfi = y2f[yln], ysi = y2s[yln];
        float lse_o_s = __shfl(lse_o, 32, 64);
        float lse_n_s = __shfl(lse_n, 32, 64);
        float vf_fl   = __shfl(xo, fln, 64);
        float vs_sl   = __shfl(xo, 32 + sln, 64);
        float nf_fl   = __shfl(xn, fln, 64);
        float ns_sl   = __shfl(xn, 32 + sln, 64);
        float vf_y    = __shfl(xo, yfi, 64);
        float vs_y    = __shfl(xo, 32 + ysi, 64);
        if (lane == 0) {
            float ce1 = lse_o   - vf_fl;
            float ce2 = lse_o_s - vs_sl;
            float stc = -expf(vf_y - lse_o) * expf(vs_y - lse_o_s);
            float ce3 = lse_n   - nf_fl;
            float ce4 = lse_n_s - ns_sl;
            part[nu] = ce1 + ce2 + stc + ce3 + ce4;
        }
    }
    #undef STAGE
    #undef ISSUE
}

// ---------------------------------------------------------------------------
// Kernel C: deterministic fixed-order loss reduction (1024 thr, f4 loads).
// ---------------------------------------------------------------------------
__global__ __launch_bounds__(1024) void loss_reduce(const float* __restrict__ part,
                                                    float* __restrict__ out) {
    __shared__ float sm[1024];
    float a = 0.f;
    const float4* p4 = (const float4*)part;
    for (int i = threadIdx.x; i < N_C/4; i += 1024) {
        float4 v = p4[i];
        a += (v.x + v.y) + (v.z + v.w);
    }
    sm[threadIdx.x] = a;
    __syncthreads();
    for (int o = 512; o >= 1; o >>= 1) {
        if ((int)threadIdx.x < o) sm[threadIdx.x] += sm[threadIdx.x + o];
        __syncthreads();
    }
    if (threadIdx.x == 0) out[0] = sm[0] * (1.0f / (float)N_C);
}

extern "C" void kernel_launch(void* const* d_in, const int* in_sizes, int n_in,
                              void* d_out, int out_size, void* d_ws, size_t ws_size,
                              hipStream_t stream) {
    (void)in_sizes; (void)n_in; (void)out_size; (void)ws_size;

    const float* f   = (const float*)d_in[0];
    const float* s   = (const float*)d_in[1];
    const float* fs  = (const float*)d_in[2];
    const float* ff  = (const float*)d_in[3];
    const float* ss  = (const float*)d_in[4];
    const float* fst = (const float*)d_in[5];
    const float* sft = (const float*)d_in[6];
    const int* fl  = (const int*)d_in[7];
    const int* sl  = (const int*)d_in[8];
    const int* yl  = (const int*)d_in[9];
    const int* y2f = (const int*)d_in[11];
    const int* y2s = (const int*)d_in[12];

    float* ws   = (float*)d_ws;
    float* fmp  = ws;
    float* fmf  = fmp + (size_t)N_C * F_C;
    float* smp  = fmf + (size_t)N_C * F_C;
    float* smf  = smp + (size_t)N_C * S_C;
    float* part = smf + (size_t)N_C * S_C;   // N_C floats

    float* outf = (float*)d_out;
    float* outs = outf + (size_t)N_C * F_C;
    float* outl = outs + (size_t)N_C * S_C;

    msg_all<<<(N_C * (F_C + S_C)) / 256, 256, 0, stream>>>(f, s, fmp, fmf, smp, smf);
    fuse_kernel<<<GRID_FZ, 256, 0, stream>>>(f, s, fs, ff, ss, fst, sft,
                                             fl, sl, yl, y2f, y2s,
                                             fmp, fmf, smp, smf,
                                             outf, outs, part);
    loss_reduce<<<1, 1024, 0, stream>>>(part, outl);
}

// Round 9
// 216.000 us; speedup vs baseline: 1.8620x; 1.8620x over previous
//
#include <hip/hip_runtime.h>
#include <math.h>

#define L_C 1024
#define B_C 32
#define F_C 24
#define S_C 12
#define N_C (L_C*B_C)   // 32768
#define DWIN 20
#define GRIDB (N_C/8)   // 4096 blocks x 4 waves; each wave owns 2 n

// ---------------------------------------------------------------------------
// Kernel A: windowed Gaussian message passing, F and S in one launch.
// ---------------------------------------------------------------------------
__global__ void msg_all(const float* __restrict__ f, const float* __restrict__ s,
                        float* __restrict__ fmp, float* __restrict__ fmf,
                        float* __restrict__ smp, float* __restrict__ smf) {
    int idx = blockIdx.x * 256 + threadIdx.x;
    const float* x; float *mp, *mf; int stride, i;
    if (idx < N_C * F_C) { x = f; mp = fmp; mf = fmf; stride = B_C*F_C; i = idx; }
    else { x = s; mp = smp; mf = smf; stride = B_C*S_C; i = idx - N_C*F_C; }
    int t = i / stride;
    float accp = 0.f, accf = 0.f;
    #pragma unroll
    for (int d = 1; d <= DWIN; ++d) {
        float w = expf(-0.125f * (float)(d * d));
        if (t >= d)      accp += w * x[i - d * stride];
        if (t + d < L_C) accf += w * x[i + d * stride];
    }
    mp[i] = accp / fmaxf((float)t, 1.0f);
    mf[i] = accf / fmaxf((float)(L_C - 1 - t), 1.0f);
}

__device__ inline float segred_max(float v) {
    #pragma unroll
    for (int o = 16; o >= 1; o >>= 1) v = fmaxf(v, __shfl_xor(v, o, 32));
    return v;
}
__device__ inline float segred_sum(float v) {
    #pragma unroll
    for (int o = 16; o >= 1; o >>= 1) v += __shfl_xor(v, o, 32);
    return v;
}

// ---------------------------------------------------------------------------
// Kernel B v9: R7's direct-global structure (no LDS, no barriers, one read
// path per byte), with TWO n's per wave interleaved (2x independent load
// chains in flight; the two serial softmax tails overlap), and the original-
// logit loss terms (ce1/ce2/struct) merged in (vF/vS already loaded).
//   F-lane g (lanes 0..23): next_f[g] ; S-lane t (lanes 32..43): next_s[t]
//   P1: vmpf . {ff[:,g] | fst[:,t]}     24x dword, stride {96|48}B
//   P2: {ff[g,:] | sft[t,:]} . vmff      6x float4
//   P3: vmps . {sft[:,g] | ss[:,t]}     12x dword, stride {96|48}B
//   P4: {fst[g,:] | ss[t,:]} . vmfs      3x float4
//   P5: k<12 both halves; k>=12 S-lanes only (no OOB)
// ---------------------------------------------------------------------------
__global__ __launch_bounds__(256, 4) void fuse_kernel(
    const float* __restrict__ f,  const float* __restrict__ s,
    const float* __restrict__ fs, const float* __restrict__ ff,
    const float* __restrict__ ss, const float* __restrict__ fst,
    const float* __restrict__ sft,
    const int* __restrict__ fl, const int* __restrict__ sl,
    const int* __restrict__ yl, const int* __restrict__ y2f,
    const int* __restrict__ y2s,
    const float* __restrict__ fmp, const float* __restrict__ fmf,
    const float* __restrict__ smp, const float* __restrict__ smf,
    float* __restrict__ outf, float* __restrict__ outs,
    float* __restrict__ part)
{
    const int tid  = threadIdx.x;
    const int w    = tid >> 6;
    const int lane = tid & 63;

    const int nu0 = __builtin_amdgcn_readfirstlane((blockIdx.x * 4 + w) * 2);
    const int nu1 = nu0 + 1;

    const bool isF    = lane < 32;
    const bool active = (lane < 24) | (lane >= 32 && lane < 44);
    const int gg = (lane < 24) ? lane : 23;
    const int tt = ((lane & 31) < 12) ? (lane & 31) : 11;

    // wave-uniform matrix bases
    const char* ffa  = (const char*)(ff  + (size_t)nu0*576);
    const char* fsa  = (const char*)(fs  + (size_t)nu0*288);
    const char* fsta = (const char*)(fst + (size_t)nu0*288);
    const char* sfta = (const char*)(sft + (size_t)nu0*288);
    const char* ssa  = (const char*)(ss  + (size_t)nu0*144);
    const char* ffb  = (const char*)(ff  + (size_t)nu1*576);
    const char* fsb  = (const char*)(fs  + (size_t)nu1*288);
    const char* fstb = (const char*)(fst + (size_t)nu1*288);
    const char* sftb = (const char*)(sft + (size_t)nu1*288);
    const char* ssb  = (const char*)(ss  + (size_t)nu1*144);

    // wave-uniform vectors (scalar loads)
    const float* vmpf0 = fmp + (size_t)nu0*24;  const float* vmpf1 = fmp + (size_t)nu1*24;
    const float* vmff0 = fmf + (size_t)nu0*24;  const float* vmff1 = fmf + (size_t)nu1*24;
    const float* vmps0 = smp + (size_t)nu0*12;  const float* vmps1 = smp + (size_t)nu1*12;
    const float* vmfs0 = smf + (size_t)nu0*12;  const float* vmfs1 = smf + (size_t)nu1*12;
    const float* vF0   = f   + (size_t)nu0*24;  const float* vF1   = f   + (size_t)nu1*24;
    const float* vS0   = s   + (size_t)nu0*12;  const float* vS1   = s   + (size_t)nu1*12;

    const int st1 = isF ? 96 : 48;   // P1 col stride (bytes)
    const int st3 = isF ? 96 : 48;   // P3 col stride
    const int st5 = isF ? 4  : 48;   // P5 first-half stride

    float a0a = 0.f, a1a = 0.f, a2a = 0.f, a3a = 0.f;
    float a0b = 0.f, a1b = 0.f, a2b = 0.f, a3b = 0.f;

    // P1: 24 col elements (both n's interleaved)
    {
        const char* qa = isF ? (ffa + gg*4) : (fsta + tt*4);
        const char* qb = isF ? (ffb + gg*4) : (fstb + tt*4);
        #pragma unroll
        for (int k = 0; k < 24; ++k) {
            a0a += vmpf0[k] * *(const float*)qa;  qa += st1;
            a0b += vmpf1[k] * *(const float*)qb;  qb += st1;
        }
    }
    // P2: row . vmff (6 float4 each)
    {
        const float4* qa = (const float4*)(isF ? (ffa + gg*96) : (sfta + tt*96));
        const float4* qb = (const float4*)(isF ? (ffb + gg*96) : (sftb + tt*96));
        #pragma unroll
        for (int k = 0; k < 6; ++k) {
            float4 x = qa[k];
            a1a += x.x*vmff0[4*k] + x.y*vmff0[4*k+1] + x.z*vmff0[4*k+2] + x.w*vmff0[4*k+3];
            float4 y = qb[k];
            a1b += y.x*vmff1[4*k] + y.y*vmff1[4*k+1] + y.z*vmff1[4*k+2] + y.w*vmff1[4*k+3];
        }
    }
    // P3: 12 col elements
    {
        const char* qa = isF ? (sfta + gg*4) : (ssa + tt*4);
        const char* qb = isF ? (sftb + gg*4) : (ssb + tt*4);
        #pragma unroll
        for (int k = 0; k < 12; ++k) {
            a2a += vmps0[k] * *(const float*)qa;  qa += st3;
            a2b += vmps1[k] * *(const float*)qb;  qb += st3;
        }
    }
    // P4: row . vmfs (3 float4)
    {
        const float4* qa = (const float4*)(isF ? (fsta + gg*48) : (ssa + tt*48));
        const float4* qb = (const float4*)(isF ? (fstb + gg*48) : (ssb + tt*48));
        #pragma unroll
        for (int k = 0; k < 3; ++k) {
            float4 x = qa[k];
            a3a += x.x*vmfs0[4*k] + x.y*vmfs0[4*k+1] + x.z*vmfs0[4*k+2] + x.w*vmfs0[4*k+3];
            float4 y = qb[k];
            a3b += y.x*vmfs1[4*k] + y.y*vmfs1[4*k+1] + y.z*vmfs1[4*k+2] + y.w*vmfs1[4*k+3];
        }
    }
    // P5: fs both directions; F lanes 12 terms, S lanes 24 (no OOB)
    {
        const char* qa = isF ? (fsa + gg*48) : (fsa + tt*4);
        const char* qb = isF ? (fsb + gg*48) : (fsb + tt*4);
        #pragma unroll
        for (int k = 0; k < 12; ++k) {
            float m0 = isF ? vS0[k] : vF0[k];
            float m1 = isF ? vS1[k] : vF1[k];
            a0a += m0 * *(const float*)qa;  qa += st5;
            a0b += m1 * *(const float*)qb;  qb += st5;
        }
        if (!isF) {
            #pragma unroll
            for (int k = 12; k < 24; ++k) {
                a1a += vF0[k] * *(const float*)qa;  qa += 48;
                a1b += vF1[k] * *(const float*)qb;  qb += 48;
            }
        }
    }

    // per-lane original logits
    float fva = 0.f, fvb = 0.f;
    if (lane < 24)                    { fva = vF0[lane];      fvb = vF1[lane]; }
    else if (lane >= 32 && lane < 44) { fva = vS0[lane - 32]; fvb = vS1[lane - 32]; }

    float nxa = fva + 0.5f * ((a0a + a1a) + (a2a + a3a));
    float nxb = fvb + 0.5f * ((a0b + a1b) + (a2b + a3b));
    float xoa = active ? fva : -INFINITY;
    float xob = active ? fvb : -INFINITY;
    float xna = active ? nxa : -INFINITY;
    float xnb = active ? nxb : -INFINITY;

    // softmax/LSE: orig + next, both n's (independent chains overlap)
    float moa = segred_max(xoa), mob = segred_max(xob);
    float eoa = expf(xoa - moa), eob = expf(xob - mob);
    float soa = segred_sum(eoa), sob = segred_sum(eob);
    float lse_oa = moa + logf(soa), lse_ob = mob + logf(sob);

    float mna = segred_max(xna), mnb = segred_max(xnb);
    float ena = expf(xna - mna), enb = expf(xnb - mnb);
    float sna = segred_sum(ena), snb = segred_sum(enb);
    float pra = ena / sna,       prb = enb / snb;
    float lse_na = mna + logf(sna), lse_nb = mnb + logf(snb);

    if (lane < 24) {
        outf[(size_t)nu0*24 + lane] = pra;
        outf[(size_t)nu1*24 + lane] = prb;
    } else if (lane >= 32 && lane < 44) {
        outs[(size_t)nu0*12 + (lane - 32)] = pra;
        outs[(size_t)nu1*12 + (lane - 32)] = prb;
    }

    // ---- loss pieces for both n's (mask identically 1) ----
    const int fln0 = fl[nu0], sln0 = sl[nu0], yln0 = yl[nu0];
    const int fln1 = fl[nu1], sln1 = sl[nu1], yln1 = yl[nu1];
    const int yfi0 = y2f[yln0], ysi0 = y2s[yln0];
    const int yfi1 = y2f[yln1], ysi1 = y2s[yln1];

    float lse_oa_s = __shfl(lse_oa, 32, 64), lse_ob_s = __shfl(lse_ob, 32, 64);
    float lse_na_s = __shfl(lse_na, 32, 64), lse_nb_s = __shfl(lse_nb, 32, 64);
    float vf_fl0 = __shfl(xoa, fln0, 64),     vf_fl1 = __shfl(xob, fln1, 64);
    float vs_sl0 = __shfl(xoa, 32 + sln0, 64), vs_sl1 = __shfl(xob, 32 + sln1, 64);
    float nf_fl0 = __shfl(xna, fln0, 64),     nf_fl1 = __shfl(xnb, fln1, 64);
    float ns_sl0 = __shfl(xna, 32 + sln0, 64), ns_sl1 = __shfl(xnb, 32 + sln1, 64);
    float vf_y0  = __shfl(xoa, yfi0, 64),     vf_y1  = __shfl(xob, yfi1, 64);
    float vs_y0  = __shfl(xoa, 32 + ysi0, 64), vs_y1  = __shfl(xob, 32 + ysi1, 64);

    if (lane == 0) {
        float l0 = (lse_oa - vf_fl0) + (lse_oa_s - vs_sl0)
                 - expf(vf_y0 - lse_oa) * expf(vs_y0 - lse_oa_s)
                 + (lse_na - nf_fl0) + (lse_na_s - ns_sl0);
        float l1 = (lse_ob - vf_fl1) + (lse_ob_s - vs_sl1)
                 - expf(vf_y1 - lse_ob) * expf(vs_y1 - lse_ob_s)
                 + (lse_nb - nf_fl1) + (lse_nb_s - ns_sl1);
        *(float2*)(part + nu0) = make_float2(l0, l1);   // nu0 even -> 8B aligned
    }
}

// ---------------------------------------------------------------------------
// Kernel C: deterministic fixed-order loss reduction (1024 thr, f4 loads).
// ---------------------------------------------------------------------------
__global__ __launch_bounds__(1024) void loss_reduce(const float* __restrict__ part,
                                                    float* __restrict__ out) {
    __shared__ float sm[1024];
    float a = 0.f;
    const float4* p4 = (const float4*)part;
    for (int i = threadIdx.x; i < N_C/4; i += 1024) {
        float4 v = p4[i];
        a += (v.x + v.y) + (v.z + v.w);
    }
    sm[threadIdx.x] = a;
    __syncthreads();
    for (int o = 512; o >= 1; o >>= 1) {
        if ((int)threadIdx.x < o) sm[threadIdx.x] += sm[threadIdx.x + o];
        __syncthreads();
    }
    if (threadIdx.x == 0) out[0] = sm[0] * (1.0f / (float)N_C);
}

extern "C" void kernel_launch(void* const* d_in, const int* in_sizes, int n_in,
                              void* d_out, int out_size, void* d_ws, size_t ws_size,
                              hipStream_t stream) {
    (void)in_sizes; (void)n_in; (void)out_size; (void)ws_size;

    const float* f   = (const float*)d_in[0];
    const float* s   = (const float*)d_in[1];
    const float* fs  = (const float*)d_in[2];
    const float* ff  = (const float*)d_in[3];
    const float* ss  = (const float*)d_in[4];
    const float* fst = (const float*)d_in[5];
    const float* sft = (const float*)d_in[6];
    const int* fl  = (const int*)d_in[7];
    const int* sl  = (const int*)d_in[8];
    const int* yl  = (const int*)d_in[9];
    const int* y2f = (const int*)d_in[11];
    const int* y2s = (const int*)d_in[12];

    float* ws   = (float*)d_ws;
    float* fmp  = ws;
    float* fmf  = fmp + (size_t)N_C * F_C;
    float* smp  = fmf + (size_t)N_C * F_C;
    float* smf  = smp + (size_t)N_C * S_C;
    float* part = smf + (size_t)N_C * S_C;   // N_C floats

    float* outf = (float*)d_out;
    float* outs = outf + (size_t)N_C * F_C;
    float* outl = outs + (size_t)N_C * S_C;

    msg_all<<<(N_C * (F_C + S_C)) / 256, 256, 0, stream>>>(f, s, fmp, fmf, smp, smf);
    fuse_kernel<<<GRIDB, 256, 0, stream>>>(f, s, fs, ff, ss, fst, sft,
                                           fl, sl, yl, y2f, y2s,
                                           fmp, fmf, smp, smf,
                                           outf, outs, part);
    loss_reduce<<<1, 1024, 0, stream>>>(part, outl);
}

// Round 10
// 100.292 us; speedup vs baseline: 4.0102x; 2.1537x over previous
//
#include <hip/hip_runtime.h>
#include <math.h>

#define L_C 1024
#define B_C 32
#define F_C 24
#define S_C 12
#define N_C (L_C*B_C)   // 32768
#define DWIN 20
#define GRIDB 2048      // 4 waves/block, NITER n per wave
#define NITER 4
#define NSTRIDE (GRIDB*4)   // 8192: n-stride per iteration

// ---------------------------------------------------------------------------
// Kernel A: windowed Gaussian message passing, F and S in one launch.
// ---------------------------------------------------------------------------
__global__ void msg_all(const float* __restrict__ f, const float* __restrict__ s,
                        float* __restrict__ fmp, float* __restrict__ fmf,
                        float* __restrict__ smp, float* __restrict__ smf) {
    int idx = blockIdx.x * 256 + threadIdx.x;
    const float* x; float *mp, *mf; int stride, i;
    if (idx < N_C * F_C) { x = f; mp = fmp; mf = fmf; stride = B_C*F_C; i = idx; }
    else { x = s; mp = smp; mf = smf; stride = B_C*S_C; i = idx - N_C*F_C; }
    int t = i / stride;
    float accp = 0.f, accf = 0.f;
    #pragma unroll
    for (int d = 1; d <= DWIN; ++d) {
        float w = expf(-0.125f * (float)(d * d));
        if (t >= d)      accp += w * x[i - d * stride];
        if (t + d < L_C) accf += w * x[i + d * stride];
    }
    mp[i] = accp / fmaxf((float)t, 1.0f);
    mf[i] = accf / fmaxf((float)(L_C - 1 - t), 1.0f);
}

__device__ inline float segred_max(float v) {
    #pragma unroll
    for (int o = 16; o >= 1; o >>= 1) v = fmaxf(v, __shfl_xor(v, o, 32));
    return v;
}
__device__ inline float segred_sum(float v) {
    #pragma unroll
    for (int o = 16; o >= 1; o >>= 1) v += __shfl_xor(v, o, 32);
    return v;
}

// ---------------------------------------------------------------------------
// Kernel B v10: wave-private dbuf LDS + counted vmcnt, ZERO barriers.
// Block = 4 waves; wave w handles n = bid*4 + w + it*8192, it=0..3.
// Per iter (fully unrolled, static buffer offsets):
//   [vmcnt(3): the 7 staging loads landed (3 = tail stores of prev iter)]
//   STAGE(other buf) -- 7x global_load_lds, overlaps entire compute
//   all 5 dot phases from LDS slice (only global path = staging)
//   softmax(orig)+softmax(next), 5 loss terms, 3 stores (newest vmem ops)
// LDS: 4 waves x 2 bufs x 6336 B = 50688 -> 3 blocks/CU = 12 independent waves.
// Slice float layout: ff@0(576) fs@576(288) fst@864(288) sft@1152(288) ss@1440(144)
// ---------------------------------------------------------------------------
__global__ __launch_bounds__(256, 3) void fuse_kernel(
    const float* __restrict__ f,  const float* __restrict__ s,
    const float* __restrict__ fs, const float* __restrict__ ff,
    const float* __restrict__ ss, const float* __restrict__ fst,
    const float* __restrict__ sft,
    const int* __restrict__ fl, const int* __restrict__ sl,
    const int* __restrict__ yl, const int* __restrict__ y2f,
    const int* __restrict__ y2s,
    const float* __restrict__ fmp, const float* __restrict__ fmf,
    const float* __restrict__ smp, const float* __restrict__ smf,
    float* __restrict__ outf, float* __restrict__ outs,
    float* __restrict__ part)
{
    __shared__ float4 L4[4*2*396];   // 50688 B
    const int tid  = threadIdx.x;
    const int w    = tid >> 6;
    const int lane = tid & 63;
    char* LBw = (char*)L4 + w*12672;          // wave's private 2-buffer region

    const int n0 = blockIdx.x*4 + w;

    // staging sources: 7 named (ptr, byte-step) pairs. Per-n f4 stream:
    // [0,144) ff | [144,216) fs | [216,288) fst | [288,360) sft | [360,396) ss
    const char *p0,*p1,*p2,*p3,*p4,*p5,*p6;
    long q0,q1,q2,q3,q4,q5,q6;
    {
        auto mk = [&](int j, const char*& P, long& S) {
            int i = 64*j + lane; if (i > 395) i = 395;
            const float* base; int off, af4;
            if (i < 144)      { base = ff;  off = i;       af4 = 144; }
            else if (i < 216) { base = fs;  off = i - 144; af4 = 72;  }
            else if (i < 288) { base = fst; off = i - 216; af4 = 72;  }
            else if (i < 360) { base = sft; off = i - 288; af4 = 72;  }
            else              { base = ss;  off = i - 360; af4 = 36;  }
            P = (const char*)base + ((size_t)n0*af4 + off)*16;
            S = (long)af4 * NSTRIDE * 16;
        };
        mk(0,p0,q0); mk(1,p1,q1); mk(2,p2,q2); mk(3,p3,q3);
        mk(4,p4,q4); mk(5,p5,q5); mk(6,p6,q6);
    }

    // dest base is wave-uniform; HW adds lane*16.
    #define ISSUE(J, PJ) \
        __builtin_amdgcn_global_load_lds( \
            (const __attribute__((address_space(1))) void*)(PJ), \
            (__attribute__((address_space(3))) void*)(LBw + bufoff + (J)*1024), \
            16, 0, 0)
    #define STAGE(BO) do { const int bufoff = (BO); \
        ISSUE(0,p0); ISSUE(1,p1); ISSUE(2,p2); ISSUE(3,p3); ISSUE(4,p4); ISSUE(5,p5); \
        if (lane < 12) { ISSUE(6,p6); } \
        p0+=q0; p1+=q1; p2+=q2; p3+=q3; p4+=q4; p5+=q5; p6+=q6; \
    } while(0)

    const bool isF    = lane < 32;
    const bool active = (lane < 24) | (lane >= 32 && lane < 44);
    const int gg = (lane < 24) ? lane : 23;
    const int tt = ((lane & 31) < 12) ? (lane & 31) : 11;

    STAGE(0);      // it=0 -> buf0

    #pragma unroll
    for (int it = 0; it < NITER; ++it) {
        const int cur = it & 1;
        // wait for this iter's staging; 3 = tail stores of previous iter
        if (it == 0) { asm volatile("s_waitcnt vmcnt(0)" ::: "memory"); }
        else         { asm volatile("s_waitcnt vmcnt(3)" ::: "memory"); }
        __builtin_amdgcn_sched_barrier(0);

        if (it + 1 < NITER) STAGE((cur^1)*6336);   // overlaps whole compute

        const int nu = __builtin_amdgcn_readfirstlane(n0 + it*NSTRIDE);
        const float* B = (const float*)(LBw + cur*6336);

        // wave-uniform vectors -> scalar (SMEM) loads
        const float* vmpf = fmp + (size_t)nu*24;
        const float* vmff = fmf + (size_t)nu*24;
        const float* vmps = smp + (size_t)nu*12;
        const float* vmfs = smf + (size_t)nu*12;
        const float* vF   = f   + (size_t)nu*24;
        const float* vS   = s   + (size_t)nu*12;

        float acc0 = 0.f, acc1 = 0.f, acc2 = 0.f, acc3 = 0.f;

        // P1: vmpf . {ff[:,g] | fst[:,t]}   (b32 cols, conflict-free)
        {
            const float* p = isF ? (B + gg) : (B + 864 + tt);
            const int st   = isF ? 24 : 12;
            #pragma unroll
            for (int k = 0; k < 24; ++k) acc0 += vmpf[k] * p[k*st];
        }
        // P2: {ff[g,:] | sft[t,:]} . vmff   (b128 rows)
        {
            const float4* r = (const float4*)(B + (isF ? gg*24 : 1152 + tt*24));
            #pragma unroll
            for (int j = 0; j < 6; ++j) {
                float4 a = r[j];
                acc1 += a.x*vmff[4*j] + a.y*vmff[4*j+1] + a.z*vmff[4*j+2] + a.w*vmff[4*j+3];
            }
        }
        // P3: vmps . {sft[:,g] | ss[:,t]}   (b32 cols)
        {
            const float* p = isF ? (B + 1152 + gg) : (B + 1440 + tt);
            const int st   = isF ? 24 : 12;
            #pragma unroll
            for (int k = 0; k < 12; ++k) acc2 += vmps[k] * p[k*st];
        }
        // P4: {fst[g,:] | ss[t,:]} . vmfs   (b128 rows, stride 48B: conflict-light)
        {
            const float4* r = (const float4*)(B + (isF ? 864 + gg*12 : 1440 + tt*12));
            #pragma unroll
            for (int j = 0; j < 3; ++j) {
                float4 a = r[j];
                acc3 += a.x*vmfs[4*j] + a.y*vmfs[4*j+1] + a.z*vmfs[4*j+2] + a.w*vmfs[4*j+3];
            }
        }
        // P5: f: fs[g,:] . s (b128) | s: f . fs[:,t] (b32)
        if (isF) {
            const float4* r = (const float4*)(B + 576 + gg*12);
            #pragma unroll
            for (int j = 0; j < 3; ++j) {
                float4 a = r[j];
                acc2 += a.x*vS[4*j] + a.y*vS[4*j+1] + a.z*vS[4*j+2] + a.w*vS[4*j+3];
            }
        } else {
            const float* p = B + 576 + tt;
            #pragma unroll
            for (int k = 0; k < 24; ++k) acc3 += vF[k] * p[k*12];
        }

        // per-lane original logit (the ONLY per-lane global loads this iter)
        float fval = 0.f;
        if (lane < 24)                    fval = vF[lane];
        else if (lane >= 32 && lane < 44) fval = vS[lane - 32];

        float nx = fval + 0.5f * ((acc0 + acc1) + (acc2 + acc3));
        float xo = active ? fval : -INFINITY;
        float xn = active ? nx   : -INFINITY;

        // softmax/LSE of original + next logits
        float mo = segred_max(xo);
        float eo = expf(xo - mo);
        float so = segred_sum(eo);
        float lse_o = mo + logf(so);

        float mn = segred_max(xn);
        float en = expf(xn - mn);
        float sn = segred_sum(en);
        float pr = en / sn;
        float lse_n = mn + logf(sn);

        // ---- exactly 3 global stores: outf | outs | part ----
        const size_t nn = (size_t)nu;
        if (lane < 24)                    outf[nn*24 + lane]        = pr;
        else if (lane >= 32 && lane < 44) outs[nn*12 + (lane - 32)] = pr;

        const int fln = fl[nu], sln = sl[nu], yln = yl[nu];
        const int yfi = y2f[yln], ysi = y2s[yln];
        float lse_o_s = __shfl(lse_o, 32, 64);
        float lse_n_s = __shfl(lse_n, 32, 64);
        float vf_fl   = __shfl(xo, fln, 64);
        float vs_sl   = __shfl(xo, 32 + sln, 64);
        float nf_fl   = __shfl(xn, fln, 64);
        float ns_sl   = __shfl(xn, 32 + sln, 64);
        float vf_y    = __shfl(xo, yfi, 64);
        float vs_y    = __shfl(xo, 32 + ysi, 64);
        if (lane == 0) {
            float ce1 = lse_o   - vf_fl;
            float ce2 = lse_o_s - vs_sl;
            float stc = -expf(vf_y - lse_o) * expf(vs_y - lse_o_s);
            float ce3 = lse_n   - nf_fl;
            float ce4 = lse_n_s - ns_sl;
            part[nu] = ce1 + ce2 + stc + ce3 + ce4;
        }
    }
    #undef STAGE
    #undef ISSUE
}

// ---------------------------------------------------------------------------
// Kernel C: deterministic fixed-order loss reduction (1024 thr, f4 loads).
// ---------------------------------------------------------------------------
__global__ __launch_bounds__(1024) void loss_reduce(const float* __restrict__ part,
                                                    float* __restrict__ out) {
    __shared__ float sm[1024];
    float a = 0.f;
    const float4* p4 = (const float4*)part;
    for (int i = threadIdx.x; i < N_C/4; i += 1024) {
        float4 v = p4[i];
        a += (v.x + v.y) + (v.z + v.w);
    }
    sm[threadIdx.x] = a;
    __syncthreads();
    for (int o = 512; o >= 1; o >>= 1) {
        if ((int)threadIdx.x < o) sm[threadIdx.x] += sm[threadIdx.x + o];
        __syncthreads();
    }
    if (threadIdx.x == 0) out[0] = sm[0] * (1.0f / (float)N_C);
}

extern "C" void kernel_launch(void* const* d_in, const int* in_sizes, int n_in,
                              void* d_out, int out_size, void* d_ws, size_t ws_size,
                              hipStream_t stream) {
    (void)in_sizes; (void)n_in; (void)out_size; (void)ws_size;

    const float* f   = (const float*)d_in[0];
    const float* s   = (const float*)d_in[1];
    const float* fs  = (const float*)d_in[2];
    const float* ff  = (const float*)d_in[3];
    const float* ss  = (const float*)d_in[4];
    const float* fst = (const float*)d_in[5];
    const float* sft = (const float*)d_in[6];
    const int* fl  = (const int*)d_in[7];
    const int* sl  = (const int*)d_in[8];
    const int* yl  = (const int*)d_in[9];
    const int* y2f = (const int*)d_in[11];
    const int* y2s = (const int*)d_in[12];

    float* ws   = (float*)d_ws;
    float* fmp  = ws;
    float* fmf  = fmp + (size_t)N_C * F_C;
    float* smp  = fmf + (size_t)N_C * F_C;
    float* smf  = smp + (size_t)N_C * S_C;
    float* part = smf + (size_t)N_C * S_C;   // N_C floats

    float* outf = (float*)d_out;
    float* outs = outf + (size_t)N_C * F_C;
    float* outl = outs + (size_t)N_C * S_C;

    msg_all<<<(N_C * (F_C + S_C)) / 256, 256, 0, stream>>>(f, s, fmp, fmf, smp, smf);
    fuse_kernel<<<GRIDB, 256, 0, stream>>>(f, s, fs, ff, ss, fst, sft,
                                           fl, sl, yl, y2f, y2s,
                                           fmp, fmf, smp, smf,
                                           outf, outs, part);
    loss_reduce<<<1, 1024, 0, stream>>>(part, outl);
}

// Round 11
// 73.704 us; speedup vs baseline: 5.4569x; 1.3607x over previous
//
#include <hip/hip_runtime.h>
#include <math.h>

#define L_C 1024
#define B_C 32
#define F_C 24
#define S_C 12
#define N_C (L_C*B_C)   // 32768
#define DWIN 20

// ---------------------------------------------------------------------------
// Kernel A: windowed Gaussian message passing, F and S in one launch.
// ---------------------------------------------------------------------------
__global__ void msg_all(const float* __restrict__ f, const float* __restrict__ s,
                        float* __restrict__ fmp, float* __restrict__ fmf,
                        float* __restrict__ smp, float* __restrict__ smf) {
    int idx = blockIdx.x * 256 + threadIdx.x;
    const float* x; float *mp, *mf; int stride, i;
    if (idx < N_C * F_C) { x = f; mp = fmp; mf = fmf; stride = B_C*F_C; i = idx; }
    else { x = s; mp = smp; mf = smf; stride = B_C*S_C; i = idx - N_C*F_C; }
    int t = i / stride;
    float accp = 0.f, accf = 0.f;
    #pragma unroll
    for (int d = 1; d <= DWIN; ++d) {
        float w = expf(-0.125f * (float)(d * d));
        if (t >= d)      accp += w * x[i - d * stride];
        if (t + d < L_C) accf += w * x[i + d * stride];
    }
    mp[i] = accp / fmaxf((float)t, 1.0f);
    mf[i] = accf / fmaxf((float)(L_C - 1 - t), 1.0f);
}

__device__ inline float segred_max(float v) {
    #pragma unroll
    for (int o = 16; o >= 1; o >>= 1) v = fmaxf(v, __shfl_xor(v, o, 32));
    return v;
}
__device__ inline float segred_sum(float v) {
    #pragma unroll
    for (int o = 16; o >= 1; o >>= 1) v += __shfl_xor(v, o, 32);
    return v;
}

// ---------------------------------------------------------------------------
// Kernel B v11: ONE-SHOT wave per n + all-LDS single-path reads, no barriers.
// Block = 4 waves = 4 n, 8192 blocks, block dies after one n per wave.
//   - wave stages its 6336B slice with 7x global_load_lds (coalesced,
//     wave-uniform dest base; the ONLY global touch of matrix data)
//   - one s_waitcnt vmcnt(0); other resident waves (24/CU) hide the latency
//   - cols from LDS b32 (conflict-free: lanes span consecutive floats),
//     rows from LDS b128
//   - softmax(orig)+softmax(next) + all 5 loss terms merged (R4 tail)
// LDS/block: 4 x 6336 = 25344 B -> 6 blocks/CU = 24 independent waves/CU.
// Slice float layout: ff@0(576) fs@576(288) fst@864(288) sft@1152(288) ss@1440(144)
// ---------------------------------------------------------------------------
__global__ __launch_bounds__(256, 6) void fuse_kernel(
    const float* __restrict__ f,  const float* __restrict__ s,
    const float* __restrict__ fs, const float* __restrict__ ff,
    const float* __restrict__ ss, const float* __restrict__ fst,
    const float* __restrict__ sft,
    const int* __restrict__ fl, const int* __restrict__ sl,
    const int* __restrict__ yl, const int* __restrict__ y2f,
    const int* __restrict__ y2s,
    const float* __restrict__ fmp, const float* __restrict__ fmf,
    const float* __restrict__ smp, const float* __restrict__ smf,
    float* __restrict__ outf, float* __restrict__ outs,
    float* __restrict__ part)
{
    __shared__ float4 L4[4*396];    // 25344 B
    const int tid  = threadIdx.x;
    const int w    = tid >> 6;
    const int lane = tid & 63;
    char* LBw = (char*)L4 + w*6336;

    const int nu = __builtin_amdgcn_readfirstlane(blockIdx.x*4 + w);

    // ---- stage this wave's slice: 7 coalesced global_load_lds ----
    // per-n f4 stream: [0,144) ff | [144,216) fs | [216,288) fst |
    //                  [288,360) sft | [360,396) ss
    {
        auto src = [&](int j) -> const char* {
            int i = 64*j + lane; if (i > 395) i = 395;
            const float* base; int off, af4;
            if (i < 144)      { base = ff;  off = i;       af4 = 144; }
            else if (i < 216) { base = fs;  off = i - 144; af4 = 72;  }
            else if (i < 288) { base = fst; off = i - 216; af4 = 72;  }
            else if (i < 360) { base = sft; off = i - 288; af4 = 72;  }
            else              { base = ss;  off = i - 360; af4 = 36;  }
            return (const char*)base + ((size_t)nu*af4 + off)*16;
        };
        #define ISSUE(J) \
            __builtin_amdgcn_global_load_lds( \
                (const __attribute__((address_space(1))) void*)(src(J)), \
                (__attribute__((address_space(3))) void*)(LBw + (J)*1024), \
                16, 0, 0)
        ISSUE(0); ISSUE(1); ISSUE(2); ISSUE(3); ISSUE(4); ISSUE(5);
        if (lane < 12) { ISSUE(6); }
        #undef ISSUE
    }

    const bool isF    = lane < 32;
    const bool active = (lane < 24) | (lane >= 32 && lane < 44);
    const int gg = (lane < 24) ? lane : 23;
    const int tt = ((lane & 31) < 12) ? (lane & 31) : 11;

    // wave-uniform vectors -> scalar (SMEM) loads (overlap staging latency)
    const float* vmpf = fmp + (size_t)nu*24;
    const float* vmff = fmf + (size_t)nu*24;
    const float* vmps = smp + (size_t)nu*12;
    const float* vmfs = smf + (size_t)nu*12;
    const float* vF   = f   + (size_t)nu*24;
    const float* vS   = s   + (size_t)nu*12;

    // per-lane original logit (independent global load, also overlaps)
    float fval = 0.f;
    if (lane < 24)                    fval = vF[lane];
    else if (lane >= 32 && lane < 44) fval = vS[lane - 32];

    const int fln = fl[nu], sln = sl[nu], yln = yl[nu];
    const int yfi = y2f[yln], ysi = y2s[yln];

    // wave's own staging landed (no barrier: slice is wave-private)
    asm volatile("s_waitcnt vmcnt(0)" ::: "memory");
    __builtin_amdgcn_sched_barrier(0);

    const float* B = (const float*)LBw;
    float acc0 = 0.f, acc1 = 0.f, acc2 = 0.f, acc3 = 0.f;

    // P1: vmpf . {ff[:,g] | fst[:,t]}   (b32 cols, lanes consecutive)
    {
        const float* p = isF ? (B + gg) : (B + 864 + tt);
        const int st   = isF ? 24 : 12;
        #pragma unroll
        for (int k = 0; k < 24; ++k) acc0 += vmpf[k] * p[k*st];
    }
    // P2: {ff[g,:] | sft[t,:]} . vmff   (b128 rows)
    {
        const float4* r = (const float4*)(B + (isF ? gg*24 : 1152 + tt*24));
        #pragma unroll
        for (int j = 0; j < 6; ++j) {
            float4 a = r[j];
            acc1 += a.x*vmff[4*j] + a.y*vmff[4*j+1] + a.z*vmff[4*j+2] + a.w*vmff[4*j+3];
        }
    }
    // P3: vmps . {sft[:,g] | ss[:,t]}   (b32 cols)
    {
        const float* p = isF ? (B + 1152 + gg) : (B + 1440 + tt);
        const int st   = isF ? 24 : 12;
        #pragma unroll
        for (int k = 0; k < 12; ++k) acc2 += vmps[k] * p[k*st];
    }
    // P4: {fst[g,:] | ss[t,:]} . vmfs   (b128 rows)
    {
        const float4* r = (const float4*)(B + (isF ? 864 + gg*12 : 1440 + tt*12));
        #pragma unroll
        for (int j = 0; j < 3; ++j) {
            float4 a = r[j];
            acc3 += a.x*vmfs[4*j] + a.y*vmfs[4*j+1] + a.z*vmfs[4*j+2] + a.w*vmfs[4*j+3];
        }
    }
    // P5: f: fs[g,:] . s (b128 rows) | s: f . fs[:,t] (b32 cols)
    if (isF) {
        const float4* r = (const float4*)(B + 576 + gg*12);
        #pragma unroll
        for (int j = 0; j < 3; ++j) {
            float4 a = r[j];
            acc2 += a.x*vS[4*j] + a.y*vS[4*j+1] + a.z*vS[4*j+2] + a.w*vS[4*j+3];
        }
    } else {
        const float* p = B + 576 + tt;
        #pragma unroll
        for (int k = 0; k < 24; ++k) acc3 += vF[k] * p[k*12];
    }

    float nx = fval + 0.5f * ((acc0 + acc1) + (acc2 + acc3));
    float xo = active ? fval : -INFINITY;
    float xn = active ? nx   : -INFINITY;

    // softmax/LSE of original + next logits
    float mo = segred_max(xo);
    float eo = expf(xo - mo);
    float so = segred_sum(eo);
    float lse_o = mo + logf(so);

    float mn = segred_max(xn);
    float en = expf(xn - mn);
    float sn = segred_sum(en);
    float pr = en / sn;
    float lse_n = mn + logf(sn);

    const size_t nn = (size_t)nu;
    if (lane < 24)                    outf[nn*24 + lane]        = pr;
    else if (lane >= 32 && lane < 44) outs[nn*12 + (lane - 32)] = pr;

    float lse_o_s = __shfl(lse_o, 32, 64);
    float lse_n_s = __shfl(lse_n, 32, 64);
    float vf_fl   = __shfl(xo, fln, 64);
    float vs_sl   = __shfl(xo, 32 + sln, 64);
    float nf_fl   = __shfl(xn, fln, 64);
    float ns_sl   = __shfl(xn, 32 + sln, 64);
    float vf_y    = __shfl(xo, yfi, 64);
    float vs_y    = __shfl(xo, 32 + ysi, 64);
    if (lane == 0) {
        float ce1 = lse_o   - vf_fl;
        float ce2 = lse_o_s - vs_sl;
        float stc = -expf(vf_y - lse_o) * expf(vs_y - lse_o_s);
        float ce3 = lse_n   - nf_fl;
        float ce4 = lse_n_s - ns_sl;
        part[nu] = ce1 + ce2 + stc + ce3 + ce4;
    }
}

// ---------------------------------------------------------------------------
// Kernel C: deterministic fixed-order loss reduction (1024 thr, f4 loads).
// ---------------------------------------------------------------------------
__global__ __launch_bounds__(1024) void loss_reduce(const float* __restrict__ part,
                                                    float* __restrict__ out) {
    __shared__ float sm[1024];
    float a = 0.f;
    const float4* p4 = (const float4*)part;
    for (int i = threadIdx.x; i < N_C/4; i += 1024) {
        float4 v = p4[i];
        a += (v.x + v.y) + (v.z + v.w);
    }
    sm[threadIdx.x] = a;
    __syncthreads();
    for (int o = 512; o >= 1; o >>= 1) {
        if ((int)threadIdx.x < o) sm[threadIdx.x] += sm[threadIdx.x + o];
        __syncthreads();
    }
    if (threadIdx.x == 0) out[0] = sm[0] * (1.0f / (float)N_C);
}

extern "C" void kernel_launch(void* const* d_in, const int* in_sizes, int n_in,
                              void* d_out, int out_size, void* d_ws, size_t ws_size,
                              hipStream_t stream) {
    (void)in_sizes; (void)n_in; (void)out_size; (void)ws_size;

    const float* f   = (const float*)d_in[0];
    const float* s   = (const float*)d_in[1];
    const float* fs  = (const float*)d_in[2];
    const float* ff  = (const float*)d_in[3];
    const float* ss  = (const float*)d_in[4];
    const float* fst = (const float*)d_in[5];
    const float* sft = (const float*)d_in[6];
    const int* fl  = (const int*)d_in[7];
    const int* sl  = (const int*)d_in[8];
    const int* yl  = (const int*)d_in[9];
    const int* y2f = (const int*)d_in[11];
    const int* y2s = (const int*)d_in[12];

    float* ws   = (float*)d_ws;
    float* fmp  = ws;
    float* fmf  = fmp + (size_t)N_C * F_C;
    float* smp  = fmf + (size_t)N_C * F_C;
    float* smf  = smp + (size_t)N_C * S_C;
    float* part = smf + (size_t)N_C * S_C;   // N_C floats

    float* outf = (float*)d_out;
    float* outs = outf + (size_t)N_C * F_C;
    float* outl = outs + (size_t)N_C * S_C;

    msg_all<<<(N_C * (F_C + S_C)) / 256, 256, 0, stream>>>(f, s, fmp, fmf, smp, smf);
    fuse_kernel<<<N_C / 4, 256, 0, stream>>>(f, s, fs, ff, ss, fst, sft,
                                             fl, sl, yl, y2f, y2s,
                                             fmp, fmf, smp, smf,
                                             outf, outs, part);
    loss_reduce<<<1, 1024, 0, stream>>>(part, outl);
}